// Round 2
// baseline (1077.397 us; speedup 1.0000x reference)
//
#include <hip/hip_runtime.h>

// ---------------------------------------------------------------------------
// SDTA block on MI355X.  B=16, C=384, H=W=56, N=3136, T=B*N=50176, NH=8, HD=48
// Workspace peak: 235,094,016 B (224.2 MiB) — lifetime-aliased regions.
// ---------------------------------------------------------------------------

typedef __attribute__((ext_vector_type(8))) short short8;
typedef __attribute__((ext_vector_type(4))) float floatx4;

#define NB 16
#define DIM 384
#define NTOK 3136
#define TTOK 50176   // NB*NTOK
#define NH 8
#define HD 48

__device__ __forceinline__ unsigned short f2bf(float f) {
  union { float f; unsigned int u; } v; v.f = f;
  unsigned int u = v.u;
  unsigned int r = (u + 0x7FFFu + ((u >> 16) & 1u)) >> 16;  // RNE
  return (unsigned short)r;
}
__device__ __forceinline__ float bf2f(unsigned short h) {
  union { unsigned int u; float f; } v; v.u = ((unsigned int)h) << 16;
  return v.f;
}

// ---------------------------------------------------------------------------
__global__ void zero_f32(float* __restrict__ p, int n) {
  int g = blockIdx.x * 256 + threadIdx.x;
  if (g < n) p[g] = 0.f;
}

// ---------------------------------------------------------------------------
// Weight transpose + bf16 convert:  wt[n*K+k] = bf16(w[k*N+n])
// ---------------------------------------------------------------------------
__global__ void wtrans(const float* __restrict__ w, unsigned short* __restrict__ wt,
                       int K, int N) {
  int g = blockIdx.x * 256 + threadIdx.x;
  if (g < K * N) {
    int k = g / N, n = g % N;
    wt[(size_t)n * K + k] = f2bf(w[g]);
  }
}

// ---------------------------------------------------------------------------
// Depthwise 3x3 conv, SAME, with two-source add: dst = conv(a+b) + bias
// ---------------------------------------------------------------------------
__global__ void dwconv(const float* __restrict__ a, long bsA,
                       const float* __restrict__ b2, long bsB,
                       const float* __restrict__ w, const float* __restrict__ bias,
                       float* __restrict__ dst) {
  int g = blockIdx.x * 256 + threadIdx.x;   // < 16*128*3136
  int xx = g % 56;
  int yy = (g / 56) % 56;
  int c  = (g / NTOK) % 128;
  int b  = g / (NTOK * 128);
  const float* pa = a  + (size_t)b * bsA + (size_t)c * NTOK;
  const float* pb = b2 + (size_t)b * bsB + (size_t)c * NTOK;
  float acc = bias[c];
  #pragma unroll
  for (int ky = 0; ky < 3; ky++) {
    int y2 = yy + ky - 1;
    if (y2 < 0 || y2 >= 56) continue;
    #pragma unroll
    for (int kx = 0; kx < 3; kx++) {
      int x2 = xx + kx - 1;
      if (x2 < 0 || x2 >= 56) continue;
      acc += w[c * 9 + ky * 3 + kx] * (pa[y2 * 56 + x2] + pb[y2 * 56 + x2]);
    }
  }
  dst[((size_t)b * 128 + c) * NTOK + yy * 56 + xx] = acc;
}

// ---------------------------------------------------------------------------
// Gather NCHW pieces -> x_flat [T,384] fp32, plus LN1 -> y bf16.
// ---------------------------------------------------------------------------
__global__ __launch_bounds__(256) void build_ln1(
    const float* __restrict__ x, const float* __restrict__ s1,
    const float* __restrict__ s2, const float* __restrict__ g,
    const float* __restrict__ bb, float* __restrict__ xflat,
    unsigned short* __restrict__ y) {
  int tkn = blockIdx.x * 4 + (threadIdx.x >> 6);
  int lane = threadIdx.x & 63;
  int b = tkn / NTOK, n = tkn % NTOK;
  float v[6];
  float s = 0.f, sq = 0.f;
  #pragma unroll
  for (int i = 0; i < 6; i++) {
    int c = lane + i * 64;
    float t;
    if (c < 128)      t = x[((size_t)b * DIM + c) * NTOK + n];
    else if (c < 256) t = s1[((size_t)b * 128 + (c - 128)) * NTOK + n];
    else              t = s2[((size_t)b * 128 + (c - 256)) * NTOK + n];
    v[i] = t; s += t; sq += t * t;
  }
  #pragma unroll
  for (int off = 32; off; off >>= 1) {
    s += __shfl_xor(s, off);
    sq += __shfl_xor(sq, off);
  }
  float mean = s * (1.f / DIM);
  float var = sq * (1.f / DIM) - mean * mean;
  float rs = rsqrtf(var + 1e-6f);
  #pragma unroll
  for (int i = 0; i < 6; i++) {
    int c = lane + i * 64;
    size_t o = (size_t)tkn * DIM + c;
    xflat[o] = v[i];
    y[o] = f2bf((v[i] - mean) * rs * g[c] + bb[c]);
  }
}

// ---------------------------------------------------------------------------
// Plain rowwise LN: fp32 [T,384] -> bf16 [T,384]
// ---------------------------------------------------------------------------
__global__ __launch_bounds__(256) void ln_rows(
    const float* __restrict__ in, const float* __restrict__ g,
    const float* __restrict__ bb, unsigned short* __restrict__ out) {
  int tkn = blockIdx.x * 4 + (threadIdx.x >> 6);
  int lane = threadIdx.x & 63;
  const float* row = in + (size_t)tkn * DIM;
  float v[6];
  float s = 0.f, sq = 0.f;
  #pragma unroll
  for (int i = 0; i < 6; i++) {
    int c = lane + i * 64;
    v[i] = row[c]; s += v[i]; sq += v[i] * v[i];
  }
  #pragma unroll
  for (int off = 32; off; off >>= 1) {
    s += __shfl_xor(s, off);
    sq += __shfl_xor(sq, off);
  }
  float mean = s * (1.f / DIM);
  float var = sq * (1.f / DIM) - mean * mean;
  float rs = rsqrtf(var + 1e-6f);
  #pragma unroll
  for (int i = 0; i < 6; i++) {
    int c = lane + i * 64;
    out[(size_t)tkn * DIM + c] = f2bf((v[i] - mean) * rs * g[c] + bb[c]);
  }
}

// ---------------------------------------------------------------------------
// Generic bf16 MFMA GEMM: C[M,N] = A[M,K] @ Bt[N,K]^T  (both row-major bf16)
// 64x64 tile, 4 waves x (2x2 of 16x16x32 mfma), K-chunk 32.
// mode 0: store bf16 | mode 1: +bias, exact GELU, bf16 | mode 2: +bias+resid fp32
// ---------------------------------------------------------------------------
__global__ __launch_bounds__(256) void gemm_bf16(
    const unsigned short* __restrict__ A, const unsigned short* __restrict__ Bt,
    const float* __restrict__ bias, const float* resid,
    void* out, int M, int N, int K, int mode) {
  __shared__ __align__(16) unsigned short As[64 * 40];
  __shared__ __align__(16) unsigned short Bs[64 * 40];
  const int tid = threadIdx.x;
  const int row0 = blockIdx.y * 64;
  const int col0 = blockIdx.x * 64;
  const int lr = tid >> 2;          // staging row 0..63
  const int lc = (tid & 3) * 8;     // staging col 0,8,16,24
  const int w = tid >> 6, lane = tid & 63;
  const int wm = (w >> 1) * 32, wn = (w & 1) * 32;
  const int quad = lane >> 4, r16 = lane & 15;

  floatx4 acc[2][2] = {};

  for (int k0 = 0; k0 < K; k0 += 32) {
    uint4 av = *(const uint4*)(A + (size_t)(row0 + lr) * K + k0 + lc);
    uint4 bv = *(const uint4*)(Bt + (size_t)(col0 + lr) * K + k0 + lc);
    *(uint4*)(&As[lr * 40 + lc]) = av;
    *(uint4*)(&Bs[lr * 40 + lc]) = bv;
    __syncthreads();
    short8 a0 = *(const short8*)(&As[(wm + r16) * 40 + quad * 8]);
    short8 a1 = *(const short8*)(&As[(wm + 16 + r16) * 40 + quad * 8]);
    short8 b0 = *(const short8*)(&Bs[(wn + r16) * 40 + quad * 8]);
    short8 b1 = *(const short8*)(&Bs[(wn + 16 + r16) * 40 + quad * 8]);
    acc[0][0] = __builtin_amdgcn_mfma_f32_16x16x32_bf16(a0, b0, acc[0][0], 0, 0, 0);
    acc[0][1] = __builtin_amdgcn_mfma_f32_16x16x32_bf16(a0, b1, acc[0][1], 0, 0, 0);
    acc[1][0] = __builtin_amdgcn_mfma_f32_16x16x32_bf16(a1, b0, acc[1][0], 0, 0, 0);
    acc[1][1] = __builtin_amdgcn_mfma_f32_16x16x32_bf16(a1, b1, acc[1][1], 0, 0, 0);
    __syncthreads();
  }

  #pragma unroll
  for (int mi = 0; mi < 2; mi++)
    #pragma unroll
    for (int ni = 0; ni < 2; ni++)
      #pragma unroll
      for (int p = 0; p < 4; p++) {
        int row = row0 + wm + mi * 16 + quad * 4 + p;
        int col = col0 + wn + ni * 16 + r16;
        size_t idx = (size_t)row * N + col;
        float v = acc[mi][ni][p];
        if (mode == 0) {
          ((unsigned short*)out)[idx] = f2bf(v);
        } else if (mode == 1) {
          v += bias[col];
          v = 0.5f * v * (1.0f + erff(v * 0.70710678118654752f));
          ((unsigned short*)out)[idx] = f2bf(v);
        } else {
          v += bias[col] + resid[idx];
          ((float*)out)[idx] = v;
        }
      }
}

// ---------------------------------------------------------------------------
// Per-(b,h,d) sum of squares over tokens for q,k (cols 0..767 of qkv).
// ---------------------------------------------------------------------------
__global__ __launch_bounds__(256) void sqnorm(const unsigned short* __restrict__ qkv,
                                              float* __restrict__ sq) {
  int b = blockIdx.x / 49, chunk = blockIdx.x % 49;
  int t = threadIdx.x;
  float a0 = 0.f, a1 = 0.f, a2 = 0.f;
  size_t base = ((size_t)b * NTOK + chunk * 64) * 1152;
  for (int r = 0; r < 64; r++) {
    size_t ro = base + (size_t)r * 1152;
    float q0 = bf2f(qkv[ro + t]);
    float q1 = bf2f(qkv[ro + t + 256]);
    float q2 = bf2f(qkv[ro + t + 512]);
    a0 += q0 * q0; a1 += q1 * q1; a2 += q2 * q2;
  }
  atomicAdd(&sq[b * 768 + t], a0);
  atomicAdd(&sq[b * 768 + t + 256], a1);
  atomicAdd(&sq[b * 768 + t + 512], a2);
}

// ---------------------------------------------------------------------------
// XCA attention matrix + softmax: attn[b,h,48,48]. One block per (b,h).
// ---------------------------------------------------------------------------
__global__ __launch_bounds__(256) void attn_kernel(
    const unsigned short* __restrict__ qkv, const float* __restrict__ sq,
    float* __restrict__ attnb) {
  __shared__ float qs[64][48];
  __shared__ float ks[64][48];
  __shared__ float Ss[48][49];
  __shared__ float qn[48], kn[48];
  int b = blockIdx.x >> 3, h = blockIdx.x & 7;
  int t = threadIdx.x;
  if (t < 48)       qn[t] = fmaxf(sqrtf(sq[b * 768 + h * HD + t]), 1e-12f);
  else if (t < 96)  kn[t - 48] = fmaxf(sqrtf(sq[b * 768 + 384 + h * HD + (t - 48)]), 1e-12f);

  int d0 = (t >> 4) * 3, e0 = (t & 15) * 3;
  float acc[3][3] = {};
  for (int chunk = 0; chunk < 49; chunk++) {
    __syncthreads();
    #pragma unroll
    for (int i = 0; i < 12; i++) {
      int idx = t + i * 256;          // < 3072
      int r = idx / 48, d = idx % 48;
      size_t ro = ((size_t)b * NTOK + chunk * 64 + r) * 1152 + h * HD;
      qs[r][d] = bf2f(qkv[ro + d]);
      ks[r][d] = bf2f(qkv[ro + 384 + d]);
    }
    __syncthreads();
    #pragma unroll 4
    for (int r = 0; r < 64; r++) {
      float q0 = qs[r][d0], q1 = qs[r][d0 + 1], q2 = qs[r][d0 + 2];
      float k0 = ks[r][e0], k1 = ks[r][e0 + 1], k2 = ks[r][e0 + 2];
      acc[0][0] += q0 * k0; acc[0][1] += q0 * k1; acc[0][2] += q0 * k2;
      acc[1][0] += q1 * k0; acc[1][1] += q1 * k1; acc[1][2] += q1 * k2;
      acc[2][0] += q2 * k0; acc[2][1] += q2 * k1; acc[2][2] += q2 * k2;
    }
  }
  #pragma unroll
  for (int i = 0; i < 3; i++)
    #pragma unroll
    for (int j = 0; j < 3; j++)
      Ss[d0 + i][e0 + j] = acc[i][j] / (qn[d0 + i] * kn[e0 + j]);
  __syncthreads();
  if (t < 48) {
    float m = -1e30f;
    for (int e = 0; e < 48; e++) m = fmaxf(m, Ss[t][e]);
    float ssum = 0.f;
    float ex[48];
    for (int e = 0; e < 48; e++) { ex[e] = expf(Ss[t][e] - m); ssum += ex[e]; }
    float inv = 1.f / ssum;
    size_t base = (((size_t)b * NH + h) * HD + t) * HD;
    for (int e = 0; e < 48; e++) attnb[base + e] = ex[e] * inv;
  }
}

// ---------------------------------------------------------------------------
// y_attn[b,n,h*48+d] = sum_e attn[b,h,d,e] * v[b,n,h,e]   -> bf16
// ---------------------------------------------------------------------------
__global__ __launch_bounds__(256) void attn_apply(
    const unsigned short* __restrict__ qkv, const float* __restrict__ attnb,
    unsigned short* __restrict__ yat) {
  __shared__ float att[48][48];
  int bh = blockIdx.x / 13, chunk = blockIdx.x % 13;
  int b = bh >> 3, h = bh & 7;
  int t = threadIdx.x;
  #pragma unroll
  for (int i = 0; i < 9; i++) {
    int idx = t + i * 256;
    if (idx < 2304) ((float*)att)[idx] = attnb[(size_t)bh * 2304 + idx];
  }
  __syncthreads();
  int n = chunk * 256 + t;
  if (n < NTOK) {
    float v[48];
    size_t ro = ((size_t)b * NTOK + n) * 1152 + 768 + h * HD;
    #pragma unroll
    for (int e = 0; e < 48; e++) v[e] = bf2f(qkv[ro + e]);
    size_t wo = ((size_t)b * NTOK + n) * DIM + h * HD;
    #pragma unroll 4
    for (int d = 0; d < 48; d++) {
      float s = 0.f;
      #pragma unroll
      for (int e = 0; e < 48; e++) s += att[d][e] * v[e];
      yat[wo + d] = f2bf(s);
    }
  }
}

// ---------------------------------------------------------------------------
// Final transpose: [B,N,C] fp32 -> [B,C,N] fp32 (32x32 LDS tiles)
// ---------------------------------------------------------------------------
__global__ __launch_bounds__(256) void transpose_out(const float* __restrict__ in,
                                                     float* __restrict__ out) {
  __shared__ float tile[32][33];
  int b = blockIdx.z, ct = blockIdx.y, nt = blockIdx.x;
  int t = threadIdx.x;
  int cc = t & 31, rr = t >> 5;
  #pragma unroll
  for (int i = 0; i < 4; i++) {
    int nn = rr + i * 8;
    tile[nn][cc] = in[((size_t)b * NTOK + nt * 32 + nn) * DIM + ct * 32 + cc];
  }
  __syncthreads();
  #pragma unroll
  for (int i = 0; i < 4; i++) {
    int c2 = rr + i * 8;
    out[((size_t)b * DIM + ct * 32 + c2) * NTOK + nt * 32 + cc] = tile[cc][c2];
  }
}

// ---------------------------------------------------------------------------
extern "C" void kernel_launch(void* const* d_in, const int* in_sizes, int n_in,
                              void* d_out, int out_size, void* d_ws, size_t ws_size,
                              hipStream_t stream) {
  const float* x       = (const float*)d_in[0];
  const float* dw_w0   = (const float*)d_in[1];
  const float* dw_b0   = (const float*)d_in[2];
  const float* dw_w1   = (const float*)d_in[3];
  const float* dw_b1   = (const float*)d_in[4];
  const float* ln1_g   = (const float*)d_in[5];
  const float* ln1_b   = (const float*)d_in[6];
  const float* qkv_w   = (const float*)d_in[7];
  const float* proj_w  = (const float*)d_in[8];
  const float* proj_b  = (const float*)d_in[9];
  const float* ln2_g   = (const float*)d_in[10];
  const float* ln2_b   = (const float*)d_in[11];
  const float* mlp1_dw = (const float*)d_in[12];
  const float* mlp1_uw = (const float*)d_in[13];
  const float* mlp1_ub = (const float*)d_in[14];
  const float* mlp2_dw = (const float*)d_in[15];
  const float* mlp2_uw = (const float*)d_in[16];
  const float* mlp2_ub = (const float*)d_in[17];
  float* out = (float*)d_out;
  char* ws = (char*)d_ws;

  // ---- workspace layout, lifetime-aliased; peak 235,094,016 B (~224 MiB) ----
  // step#:  1 dw1 | 2 dw2 | 3 build_ln1 | 4 qkv gemm | 5 sqnorm | 6 attn |
  //         7 attn_apply | 8 proj gemm | 9 ln2 | 10 mlp_down | 11 mlp_mid(x2) |
  //         12 final gemm | 13 transpose
  float*          xflat = (float*)(ws + 0);                    // 77,070,336  alive 3-8
  unsigned short* qkvb  = (unsigned short*)(ws + 77070336);    // 115,605,504 alive 4-7
  float*          s1ws  = (float*)(ws + 77070336);             // 25,690,112  alive 1-3
  float*          s2ws  = (float*)(ws + 102760448);            // 25,690,112  alive 2-3
  unsigned short* ybf   = (unsigned short*)(ws + 192675840);   // 38,535,168  alive 3-4
  unsigned short* yat   = (unsigned short*)(ws + 192675840);   // 38,535,168  alive 7-8
  float*          xres  = (float*)(ws + 77070336);             // 77,070,336  alive 8-13
  unsigned short* zbf   = (unsigned short*)(ws + 0);           // 38,535,168  alive 9-10
  unsigned short* h1    = (unsigned short*)(ws + 38535168);    // 19,267,584  alive 10-11
  unsigned short* h3    = (unsigned short*)(ws + 57802752);    // 19,267,584  alive 11-12
  unsigned short* h2    = (unsigned short*)(ws + 154140672);   // 77,070,336  alive 11 (half-T)
  unsigned short* qkvT  = (unsigned short*)(ws + 231211008);   //    884,736
  unsigned short* projT = (unsigned short*)(ws + 232095744);   //    294,912
  unsigned short* m1dT  = (unsigned short*)(ws + 232390656);   //    147,456
  unsigned short* m1uT  = (unsigned short*)(ws + 232538112);   //    589,824
  unsigned short* m2dT  = (unsigned short*)(ws + 233127936);   //    589,824
  unsigned short* m2uT  = (unsigned short*)(ws + 233717760);   //    147,456
  float*          sqbuf = (float*)(ws + 233865216);            //     49,152
  float*          attnb = (float*)(ws + 233914368);            //  1,179,648 -> end 235,094,016

  zero_f32<<<48, 256, 0, stream>>>(sqbuf, NB * 768);

  // weights -> [N,K] bf16
  wtrans<<<1728, 256, 0, stream>>>(qkv_w, qkvT, 384, 1152);
  wtrans<<<576, 256, 0, stream>>>(proj_w, projT, 384, 384);
  wtrans<<<288, 256, 0, stream>>>(mlp1_dw, m1dT, 384, 192);
  wtrans<<<1152, 256, 0, stream>>>(mlp1_uw, m1uT, 192, 1536);
  wtrans<<<1152, 256, 0, stream>>>(mlp2_dw, m2dT, 1536, 192);
  wtrans<<<288, 256, 0, stream>>>(mlp2_uw, m2uT, 192, 384);

  // depthwise chain: s1' = conv(s1+s0), s2' = conv(s2+s1')
  dwconv<<<25088, 256, 0, stream>>>(x + 128 * NTOK, (long)DIM * NTOK,
                                    x, (long)DIM * NTOK, dw_w0, dw_b0, s1ws);
  dwconv<<<25088, 256, 0, stream>>>(x + 256 * NTOK, (long)DIM * NTOK,
                                    s1ws, (long)128 * NTOK, dw_w1, dw_b1, s2ws);

  // gather + LN1
  build_ln1<<<12544, 256, 0, stream>>>(x, s1ws, s2ws, ln1_g, ln1_b, xflat, ybf);

  // qkv = y @ qkv_w   [50176,1152] bf16
  gemm_bf16<<<dim3(18, 784), 256, 0, stream>>>(ybf, qkvT, nullptr, nullptr,
                                               qkvb, TTOK, 1152, 384, 0);
  // token-dim L2 norms of q,k
  sqnorm<<<NB * 49, 256, 0, stream>>>(qkvb, sqbuf);
  // 48x48 XCA attention + softmax
  attn_kernel<<<NB * NH, 256, 0, stream>>>(qkvb, sqbuf, attnb);
  // y_attn = attn @ v  -> bf16 [T,384]
  attn_apply<<<NB * NH * 13, 256, 0, stream>>>(qkvb, attnb, yat);

  // x_res = x_flat + y_attn @ proj_w + proj_b   (fp32)
  gemm_bf16<<<dim3(6, 784), 256, 0, stream>>>(yat, projT, proj_b, xflat,
                                              xres, TTOK, 384, 384, 2);
  // z = LN2(x_res)  bf16
  ln_rows<<<12544, 256, 0, stream>>>(xres, ln2_g, ln2_b, zbf);
  // MLP down: h1 = z @ mlp1_dw  [T,192]
  gemm_bf16<<<dim3(3, 784), 256, 0, stream>>>(zbf, m1dT, nullptr, nullptr,
                                              h1, TTOK, 192, 384, 0);
  // MLP mid in two half-T passes through one 77MB h2 buffer:
  // h2 = gelu(h1 @ mlp1_uw + b) [25088,1536]; h3 = h2 @ mlp2_dw [25088,192]
  for (int half = 0; half < 2; half++) {
    const unsigned short* h1p = h1 + (size_t)half * 25088 * 192;
    unsigned short* h3p = h3 + (size_t)half * 25088 * 192;
    gemm_bf16<<<dim3(24, 392), 256, 0, stream>>>(h1p, m1uT, mlp1_ub, nullptr,
                                                 h2, 25088, 1536, 192, 1);
    gemm_bf16<<<dim3(3, 392), 256, 0, stream>>>(h2, m2dT, nullptr, nullptr,
                                                h3p, 25088, 192, 1536, 0);
  }
  // out_flat = x_res + h3 @ mlp2_uw + b   (in-place over x_res)
  gemm_bf16<<<dim3(6, 784), 256, 0, stream>>>(h3, m2uT, mlp2_ub, xres,
                                              xres, TTOK, 384, 192, 2);
  // [B,N,C] -> [B,C,H,W]
  transpose_out<<<dim3(98, 12, 16), 256, 0, stream>>>(xres, out);
}

// Round 3
// 992.177 us; speedup vs baseline: 1.0859x; 1.0859x over previous
//
#include <hip/hip_runtime.h>

// ---------------------------------------------------------------------------
// SDTA block on MI355X.  B=16, C=384, H=W=56, N=3136, T=B*N=50176, NH=8, HD=48
// Workspace peak: 235,094,016 B (224.2 MiB) — lifetime-aliased regions.
// ---------------------------------------------------------------------------

typedef __attribute__((ext_vector_type(8))) short short8;
typedef __attribute__((ext_vector_type(4))) float floatx4;

#define NB 16
#define DIM 384
#define NTOK 3136
#define TTOK 50176   // NB*NTOK
#define NH 8
#define HD 48

__device__ __forceinline__ unsigned short f2bf(float f) {
  union { float f; unsigned int u; } v; v.f = f;
  unsigned int u = v.u;
  unsigned int r = (u + 0x7FFFu + ((u >> 16) & 1u)) >> 16;  // RNE
  return (unsigned short)r;
}
__device__ __forceinline__ float bf2f(unsigned short h) {
  union { unsigned int u; float f; } v; v.u = ((unsigned int)h) << 16;
  return v.f;
}

// async global->LDS, 16B per lane; LDS dest is wave-uniform base + lane*16.
__device__ __forceinline__ void gload_lds16(const unsigned short* g, unsigned short* l) {
  __builtin_amdgcn_global_load_lds(
      (const __attribute__((address_space(1))) unsigned int*)g,
      (__attribute__((address_space(3))) unsigned int*)l, 16, 0, 0);
}

// ---------------------------------------------------------------------------
__global__ void zero_f32(float* __restrict__ p, int n) {
  int g = blockIdx.x * 256 + threadIdx.x;
  if (g < n) p[g] = 0.f;
}

// ---------------------------------------------------------------------------
// Weight transpose + bf16 convert:  wt[n*K+k] = bf16(w[k*N+n])
// ---------------------------------------------------------------------------
__global__ void wtrans(const float* __restrict__ w, unsigned short* __restrict__ wt,
                       int K, int N) {
  int g = blockIdx.x * 256 + threadIdx.x;
  if (g < K * N) {
    int k = g / N, n = g % N;
    wt[(size_t)n * K + k] = f2bf(w[g]);
  }
}

// ---------------------------------------------------------------------------
// Depthwise 3x3 conv, SAME, with two-source add: dst = conv(a+b) + bias
// ---------------------------------------------------------------------------
__global__ void dwconv(const float* __restrict__ a, long bsA,
                       const float* __restrict__ b2, long bsB,
                       const float* __restrict__ w, const float* __restrict__ bias,
                       float* __restrict__ dst) {
  int g = blockIdx.x * 256 + threadIdx.x;   // < 16*128*3136
  int xx = g % 56;
  int yy = (g / 56) % 56;
  int c  = (g / NTOK) % 128;
  int b  = g / (NTOK * 128);
  const float* pa = a  + (size_t)b * bsA + (size_t)c * NTOK;
  const float* pb = b2 + (size_t)b * bsB + (size_t)c * NTOK;
  float acc = bias[c];
  #pragma unroll
  for (int ky = 0; ky < 3; ky++) {
    int y2 = yy + ky - 1;
    if (y2 < 0 || y2 >= 56) continue;
    #pragma unroll
    for (int kx = 0; kx < 3; kx++) {
      int x2 = xx + kx - 1;
      if (x2 < 0 || x2 >= 56) continue;
      acc += w[c * 9 + ky * 3 + kx] * (pa[y2 * 56 + x2] + pb[y2 * 56 + x2]);
    }
  }
  dst[((size_t)b * 128 + c) * NTOK + yy * 56 + xx] = acc;
}

// ---------------------------------------------------------------------------
// Gather NCHW pieces -> x_flat [T,384] fp32, plus LN1 -> y bf16.
// ---------------------------------------------------------------------------
__global__ __launch_bounds__(256) void build_ln1(
    const float* __restrict__ x, const float* __restrict__ s1,
    const float* __restrict__ s2, const float* __restrict__ g,
    const float* __restrict__ bb, float* __restrict__ xflat,
    unsigned short* __restrict__ y) {
  int tkn = blockIdx.x * 4 + (threadIdx.x >> 6);
  int lane = threadIdx.x & 63;
  int b = tkn / NTOK, n = tkn % NTOK;
  float v[6];
  float s = 0.f, sq = 0.f;
  #pragma unroll
  for (int i = 0; i < 6; i++) {
    int c = lane + i * 64;
    float t;
    if (c < 128)      t = x[((size_t)b * DIM + c) * NTOK + n];
    else if (c < 256) t = s1[((size_t)b * 128 + (c - 128)) * NTOK + n];
    else              t = s2[((size_t)b * 128 + (c - 256)) * NTOK + n];
    v[i] = t; s += t; sq += t * t;
  }
  #pragma unroll
  for (int off = 32; off; off >>= 1) {
    s += __shfl_xor(s, off);
    sq += __shfl_xor(sq, off);
  }
  float mean = s * (1.f / DIM);
  float var = sq * (1.f / DIM) - mean * mean;
  float rs = rsqrtf(var + 1e-6f);
  #pragma unroll
  for (int i = 0; i < 6; i++) {
    int c = lane + i * 64;
    size_t o = (size_t)tkn * DIM + c;
    xflat[o] = v[i];
    y[o] = f2bf((v[i] - mean) * rs * g[c] + bb[c]);
  }
}

// ---------------------------------------------------------------------------
// Plain rowwise LN: fp32 [T,384] -> bf16 [T,384]
// ---------------------------------------------------------------------------
__global__ __launch_bounds__(256) void ln_rows(
    const float* __restrict__ in, const float* __restrict__ g,
    const float* __restrict__ bb, unsigned short* __restrict__ out) {
  int tkn = blockIdx.x * 4 + (threadIdx.x >> 6);
  int lane = threadIdx.x & 63;
  const float* row = in + (size_t)tkn * DIM;
  float v[6];
  float s = 0.f, sq = 0.f;
  #pragma unroll
  for (int i = 0; i < 6; i++) {
    int c = lane + i * 64;
    v[i] = row[c]; s += v[i]; sq += v[i] * v[i];
  }
  #pragma unroll
  for (int off = 32; off; off >>= 1) {
    s += __shfl_xor(s, off);
    sq += __shfl_xor(sq, off);
  }
  float mean = s * (1.f / DIM);
  float var = sq * (1.f / DIM) - mean * mean;
  float rs = rsqrtf(var + 1e-6f);
  #pragma unroll
  for (int i = 0; i < 6; i++) {
    int c = lane + i * 64;
    out[(size_t)tkn * DIM + c] = f2bf((v[i] - mean) * rs * g[c] + bb[c]);
  }
}

// ---------------------------------------------------------------------------
// 128-tile MFMA GEMM (m97 structure): C[M,N] = A[M,K] @ Bt[N,K]^T, bf16 in.
// BM=128, BK=32, 256 threads (4 waves).
//   BN=128: wave grid 2x2, wave tile 64x64 (4x4 accs of 16x16x32)
//   BN=64 : wave grid 4x1, wave tile 32x64 (2x4 accs)
// Staging via global_load_lds width=16 into UNPADDED row-major LDS tiles
// (wave-uniform base + lane*16 — padding would break the layout).
// MODE 0: store bf16 | MODE 1: +bias, exact GELU, bf16 | MODE 2: +bias+resid fp32
// M % 128 == 0, N % BN == 0, K % 32 == 0 (no guards).
// ---------------------------------------------------------------------------
template<int BN, int MODE>
__global__ __launch_bounds__(256) void gemm128(
    const unsigned short* __restrict__ A, const unsigned short* __restrict__ Bt,
    const float* __restrict__ bias, const float* __restrict__ resid,
    void* __restrict__ out, int M, int N, int K) {
  constexpr int MT = (BN == 128) ? 4 : 2;   // 16-row m tiles per wave
  constexpr int NT = 4;                     // 16-col n tiles per wave
  __shared__ __align__(16) unsigned short As[128 * 32];
  __shared__ __align__(16) unsigned short Bs[BN * 32];
  const int tid = threadIdx.x;
  const int w = tid >> 6, lane = tid & 63;
  const int quad = lane >> 4, r16 = lane & 15;
  const int row0 = blockIdx.y * 128, col0 = blockIdx.x * BN;
  const int wm = (BN == 128) ? (w >> 1) * 64 : w * 32;
  const int wn = (BN == 128) ? (w & 1) * 64 : 0;
  const int lrow = lane >> 2;           // 0..15 within a 16-row group
  const int lcol = (lane & 3) * 8;      // 0,8,16,24

  // per-wave staging source pointers (this wave loads A rows [32w,32w+32) and
  // B rows [32w,32w+32) for BN=128, or B rows [16w,16w+16) for BN=64)
  const unsigned short* aP0 = A + (size_t)(row0 + w * 32 + lrow) * K + lcol;
  const unsigned short* aP1 = aP0 + (size_t)16 * K;
  const unsigned short* bP0 = Bt + (size_t)(col0 + ((BN == 128) ? w * 32 : w * 16) + lrow) * K + lcol;
  const unsigned short* bP1 = bP0 + (size_t)16 * K;

  floatx4 acc[MT][NT] = {};

  for (int k0 = 0; k0 < K; k0 += 32) {
    gload_lds16(aP0 + k0, &As[(2 * w) * 512]);
    gload_lds16(aP1 + k0, &As[(2 * w + 1) * 512]);
    if (BN == 128) {
      gload_lds16(bP0 + k0, &Bs[(2 * w) * 512]);
      gload_lds16(bP1 + k0, &Bs[(2 * w + 1) * 512]);
    } else {
      gload_lds16(bP0 + k0, &Bs[w * 512]);
    }
    __syncthreads();
    short8 af[MT], bfr[NT];
    #pragma unroll
    for (int mi = 0; mi < MT; mi++)
      af[mi] = *(const short8*)(&As[(wm + mi * 16 + r16) * 32 + quad * 8]);
    #pragma unroll
    for (int ni = 0; ni < NT; ni++)
      bfr[ni] = *(const short8*)(&Bs[(wn + ni * 16 + r16) * 32 + quad * 8]);
    #pragma unroll
    for (int mi = 0; mi < MT; mi++)
      #pragma unroll
      for (int ni = 0; ni < NT; ni++)
        acc[mi][ni] = __builtin_amdgcn_mfma_f32_16x16x32_bf16(af[mi], bfr[ni], acc[mi][ni], 0, 0, 0);
    __syncthreads();
  }

  #pragma unroll
  for (int mi = 0; mi < MT; mi++)
    #pragma unroll
    for (int ni = 0; ni < NT; ni++)
      #pragma unroll
      for (int p = 0; p < 4; p++) {
        int row = row0 + wm + mi * 16 + quad * 4 + p;
        int col = col0 + wn + ni * 16 + r16;
        size_t idx = (size_t)row * N + col;
        float v = acc[mi][ni][p];
        if (MODE == 0) {
          ((unsigned short*)out)[idx] = f2bf(v);
        } else if (MODE == 1) {
          v += bias[col];
          v = 0.5f * v * (1.0f + erff(v * 0.70710678118654752f));
          ((unsigned short*)out)[idx] = f2bf(v);
        } else {
          v += bias[col] + resid[idx];
          ((float*)out)[idx] = v;
        }
      }
}

// ---------------------------------------------------------------------------
// XCA attention partials: one block per (b,h,chunk-of-64-tokens).
// Accumulates S[b,h,48,48] += q_chunk^T-outer, and q^2/k^2 column sums,
// via global atomicAdd.  Also covers what sqnorm did before.
// ---------------------------------------------------------------------------
__global__ __launch_bounds__(256) void attn_partial(
    const unsigned short* __restrict__ qkv, float* __restrict__ S,
    float* __restrict__ sq) {
  __shared__ float qs[64][48];
  __shared__ float ks[64][48];
  int blk = blockIdx.x;                 // b*392 + h*49 + chunk
  int b = blk / 392, rem = blk % 392;
  int h = rem / 49, chunk = rem % 49;
  int t = threadIdx.x;
  #pragma unroll
  for (int i = 0; i < 12; i++) {
    int idx = t + i * 256;              // < 3072
    int r = idx / 48, d = idx % 48;
    size_t ro = ((size_t)b * NTOK + chunk * 64 + r) * 1152 + h * HD;
    qs[r][d] = bf2f(qkv[ro + d]);
    ks[r][d] = bf2f(qkv[ro + 384 + d]);
  }
  __syncthreads();
  int d0 = (t >> 4) * 3, e0 = (t & 15) * 3;
  float acc[3][3] = {};
  #pragma unroll 4
  for (int r = 0; r < 64; r++) {
    float q0 = qs[r][d0], q1 = qs[r][d0 + 1], q2 = qs[r][d0 + 2];
    float k0 = ks[r][e0], k1 = ks[r][e0 + 1], k2 = ks[r][e0 + 2];
    acc[0][0] += q0 * k0; acc[0][1] += q0 * k1; acc[0][2] += q0 * k2;
    acc[1][0] += q1 * k0; acc[1][1] += q1 * k1; acc[1][2] += q1 * k2;
    acc[2][0] += q2 * k0; acc[2][1] += q2 * k1; acc[2][2] += q2 * k2;
  }
  float* Sp = S + (size_t)(b * NH + h) * 2304;
  #pragma unroll
  for (int i = 0; i < 3; i++)
    #pragma unroll
    for (int j = 0; j < 3; j++)
      atomicAdd(&Sp[(d0 + i) * 48 + e0 + j], acc[i][j]);
  // column sums of squares (waves 0 and 1 run these in parallel)
  if (t < 48) {
    float s = 0.f;
    for (int r = 0; r < 64; r++) s += qs[r][t] * qs[r][t];
    atomicAdd(&sq[b * 768 + h * HD + t], s);
  } else if (t >= 64 && t < 112) {
    int e = t - 64;
    float s = 0.f;
    for (int r = 0; r < 64; r++) s += ks[r][e] * ks[r][e];
    atomicAdd(&sq[b * 768 + 384 + h * HD + e], s);
  }
}

// ---------------------------------------------------------------------------
// Normalize by q/k L2 norms + row softmax, in place over S. 128 blocks.
// ---------------------------------------------------------------------------
__global__ __launch_bounds__(64) void attn_softmax(
    float* __restrict__ S, const float* __restrict__ sq) {
  int bh = blockIdx.x, b = bh >> 3, h = bh & 7;
  int t = threadIdx.x;
  if (t >= 48) return;
  float qn = fmaxf(sqrtf(sq[b * 768 + h * HD + t]), 1e-12f);
  float* Sp = S + (size_t)bh * 2304 + t * 48;
  float row[48];
  float m = -1e30f;
  for (int e = 0; e < 48; e++) {
    float kn = fmaxf(sqrtf(sq[b * 768 + 384 + h * HD + e]), 1e-12f);
    row[e] = Sp[e] / (qn * kn);
    m = fmaxf(m, row[e]);
  }
  float ssum = 0.f;
  for (int e = 0; e < 48; e++) { row[e] = expf(row[e] - m); ssum += row[e]; }
  float inv = 1.f / ssum;
  for (int e = 0; e < 48; e++) Sp[e] = row[e] * inv;
}

// ---------------------------------------------------------------------------
// y_attn[b,n,h*48+d] = sum_e attn[b,h,d,e] * v[b,n,h,e]   -> bf16
// ---------------------------------------------------------------------------
__global__ __launch_bounds__(256) void attn_apply(
    const unsigned short* __restrict__ qkv, const float* __restrict__ attnb,
    unsigned short* __restrict__ yat) {
  __shared__ float att[48][48];
  int bh = blockIdx.x / 13, chunk = blockIdx.x % 13;
  int b = bh >> 3, h = bh & 7;
  int t = threadIdx.x;
  #pragma unroll
  for (int i = 0; i < 9; i++) {
    int idx = t + i * 256;
    if (idx < 2304) ((float*)att)[idx] = attnb[(size_t)bh * 2304 + idx];
  }
  __syncthreads();
  int n = chunk * 256 + t;
  if (n < NTOK) {
    float v[48];
    size_t ro = ((size_t)b * NTOK + n) * 1152 + 768 + h * HD;
    #pragma unroll
    for (int e = 0; e < 48; e++) v[e] = bf2f(qkv[ro + e]);
    size_t wo = ((size_t)b * NTOK + n) * DIM + h * HD;
    #pragma unroll 4
    for (int d = 0; d < 48; d++) {
      float s = 0.f;
      #pragma unroll
      for (int e = 0; e < 48; e++) s += att[d][e] * v[e];
      yat[wo + d] = f2bf(s);
    }
  }
}

// ---------------------------------------------------------------------------
// Final transpose: [B,N,C] fp32 -> [B,C,N] fp32 (32x32 LDS tiles)
// ---------------------------------------------------------------------------
__global__ __launch_bounds__(256) void transpose_out(const float* __restrict__ in,
                                                     float* __restrict__ out) {
  __shared__ float tile[32][33];
  int b = blockIdx.z, ct = blockIdx.y, nt = blockIdx.x;
  int t = threadIdx.x;
  int cc = t & 31, rr = t >> 5;
  #pragma unroll
  for (int i = 0; i < 4; i++) {
    int nn = rr + i * 8;
    tile[nn][cc] = in[((size_t)b * NTOK + nt * 32 + nn) * DIM + ct * 32 + cc];
  }
  __syncthreads();
  #pragma unroll
  for (int i = 0; i < 4; i++) {
    int c2 = rr + i * 8;
    out[((size_t)b * DIM + ct * 32 + c2) * NTOK + nt * 32 + cc] = tile[cc][c2];
  }
}

// ---------------------------------------------------------------------------
extern "C" void kernel_launch(void* const* d_in, const int* in_sizes, int n_in,
                              void* d_out, int out_size, void* d_ws, size_t ws_size,
                              hipStream_t stream) {
  const float* x       = (const float*)d_in[0];
  const float* dw_w0   = (const float*)d_in[1];
  const float* dw_b0   = (const float*)d_in[2];
  const float* dw_w1   = (const float*)d_in[3];
  const float* dw_b1   = (const float*)d_in[4];
  const float* ln1_g   = (const float*)d_in[5];
  const float* ln1_b   = (const float*)d_in[6];
  const float* qkv_w   = (const float*)d_in[7];
  const float* proj_w  = (const float*)d_in[8];
  const float* proj_b  = (const float*)d_in[9];
  const float* ln2_g   = (const float*)d_in[10];
  const float* ln2_b   = (const float*)d_in[11];
  const float* mlp1_dw = (const float*)d_in[12];
  const float* mlp1_uw = (const float*)d_in[13];
  const float* mlp1_ub = (const float*)d_in[14];
  const float* mlp2_dw = (const float*)d_in[15];
  const float* mlp2_uw = (const float*)d_in[16];
  const float* mlp2_ub = (const float*)d_in[17];
  float* out = (float*)d_out;
  char* ws = (char*)d_ws;

  // ---- workspace layout, lifetime-aliased; peak 235,094,016 B (~224 MiB) ----
  float*          xflat = (float*)(ws + 0);                    // 77,070,336  alive 3-8
  unsigned short* qkvb  = (unsigned short*)(ws + 77070336);    // 115,605,504 alive 4-7
  float*          s1ws  = (float*)(ws + 77070336);             // 25,690,112  alive 1-3
  float*          s2ws  = (float*)(ws + 102760448);            // 25,690,112  alive 2-3
  unsigned short* ybf   = (unsigned short*)(ws + 192675840);   // 38,535,168  alive 3-4
  unsigned short* yat   = (unsigned short*)(ws + 192675840);   // 38,535,168  alive 7-8
  float*          xres  = (float*)(ws + 77070336);             // 77,070,336  alive 8-13
  unsigned short* zbf   = (unsigned short*)(ws + 0);           // 38,535,168  alive 9-10
  unsigned short* h1    = (unsigned short*)(ws + 38535168);    // 19,267,584  alive 10-11
  unsigned short* h3    = (unsigned short*)(ws + 57802752);    // 19,267,584  alive 11-12
  unsigned short* h2    = (unsigned short*)(ws + 154140672);   // 77,070,336  alive 11 (half-T)
  unsigned short* qkvT  = (unsigned short*)(ws + 231211008);   //    884,736
  unsigned short* projT = (unsigned short*)(ws + 232095744);   //    294,912
  unsigned short* m1dT  = (unsigned short*)(ws + 232390656);   //    147,456
  unsigned short* m1uT  = (unsigned short*)(ws + 232538112);   //    589,824
  unsigned short* m2dT  = (unsigned short*)(ws + 233127936);   //    589,824
  unsigned short* m2uT  = (unsigned short*)(ws + 233717760);   //    147,456
  float*          sqbuf = (float*)(ws + 233865216);            //     49,152
  float*          attnb = (float*)(ws + 233914368);            //  1,179,648 -> 235,094,016

  // zero sqbuf + attnb (contiguous: 12288 + 294912 = 307200 floats)
  zero_f32<<<1200, 256, 0, stream>>>(sqbuf, 307200);

  // weights -> [N,K] bf16
  wtrans<<<1728, 256, 0, stream>>>(qkv_w, qkvT, 384, 1152);
  wtrans<<<576, 256, 0, stream>>>(proj_w, projT, 384, 384);
  wtrans<<<288, 256, 0, stream>>>(mlp1_dw, m1dT, 384, 192);
  wtrans<<<1152, 256, 0, stream>>>(mlp1_uw, m1uT, 192, 1536);
  wtrans<<<1152, 256, 0, stream>>>(mlp2_dw, m2dT, 1536, 192);
  wtrans<<<288, 256, 0, stream>>>(mlp2_uw, m2uT, 192, 384);

  // depthwise chain: s1' = conv(s1+s0), s2' = conv(s2+s1')
  dwconv<<<25088, 256, 0, stream>>>(x + 128 * NTOK, (long)DIM * NTOK,
                                    x, (long)DIM * NTOK, dw_w0, dw_b0, s1ws);
  dwconv<<<25088, 256, 0, stream>>>(x + 256 * NTOK, (long)DIM * NTOK,
                                    s1ws, (long)128 * NTOK, dw_w1, dw_b1, s2ws);

  // gather + LN1
  build_ln1<<<12544, 256, 0, stream>>>(x, s1ws, s2ws, ln1_g, ln1_b, xflat, ybf);

  // qkv = y @ qkv_w   [50176,1152] bf16
  gemm128<128, 0><<<dim3(9, 392), 256, 0, stream>>>(ybf, qkvT, nullptr, nullptr,
                                                    qkvb, TTOK, 1152, 384);
  // XCA: partial S + sq sums (6272 blocks), then softmax (128 blocks)
  attn_partial<<<NB * NH * 49, 256, 0, stream>>>(qkvb, attnb, sqbuf);
  attn_softmax<<<NB * NH, 64, 0, stream>>>(attnb, sqbuf);
  // y_attn = attn @ v  -> bf16 [T,384]
  attn_apply<<<NB * NH * 13, 256, 0, stream>>>(qkvb, attnb, yat);

  // x_res = x_flat + y_attn @ proj_w + proj_b   (fp32)
  gemm128<128, 2><<<dim3(3, 392), 256, 0, stream>>>(yat, projT, proj_b, xflat,
                                                    xres, TTOK, 384, 384);
  // z = LN2(x_res)  bf16
  ln_rows<<<12544, 256, 0, stream>>>(xres, ln2_g, ln2_b, zbf);
  // MLP down: h1 = z @ mlp1_dw  [T,192]
  gemm128<64, 0><<<dim3(3, 392), 256, 0, stream>>>(zbf, m1dT, nullptr, nullptr,
                                                   h1, TTOK, 192, 384);
  // MLP mid in two half-T passes through one 77MB h2 buffer
  for (int half = 0; half < 2; half++) {
    const unsigned short* h1p = h1 + (size_t)half * 25088 * 192;
    unsigned short* h3p = h3 + (size_t)half * 25088 * 192;
    gemm128<128, 1><<<dim3(12, 196), 256, 0, stream>>>(h1p, m1uT, mlp1_ub, nullptr,
                                                       h2, 25088, 1536, 192);
    gemm128<64, 0><<<dim3(3, 196), 256, 0, stream>>>(h2, m2dT, nullptr, nullptr,
                                                     h3p, 25088, 192, 1536);
  }
  // out_flat = x_res + h3 @ mlp2_uw + b   (in-place over x_res)
  gemm128<128, 2><<<dim3(3, 392), 256, 0, stream>>>(h3, m2uT, mlp2_ub, xres,
                                                    xres, TTOK, 384, 192);
  // [B,N,C] -> [B,C,H,W]
  transpose_out<<<dim3(98, 12, 16), 256, 0, stream>>>(xres, out);
}

// Round 4
// 885.791 us; speedup vs baseline: 1.2163x; 1.1201x over previous
//
#include <hip/hip_runtime.h>

// ---------------------------------------------------------------------------
// SDTA block on MI355X.  B=16, C=384, H=W=56, N=3136, T=B*N=50176, NH=8, HD=48
// Workspace peak: 235,094,016 B (224.2 MiB) — lifetime-aliased regions.
// ---------------------------------------------------------------------------

typedef __attribute__((ext_vector_type(8))) short short8;
typedef __attribute__((ext_vector_type(4))) float floatx4;

#define NB 16
#define DIM 384
#define NTOK 3136
#define TTOK 50176   // NB*NTOK
#define NH 8
#define HD 48

__device__ __forceinline__ unsigned short f2bf(float f) {
  union { float f; unsigned int u; } v; v.f = f;
  unsigned int u = v.u;
  unsigned int r = (u + 0x7FFFu + ((u >> 16) & 1u)) >> 16;  // RNE
  return (unsigned short)r;
}
__device__ __forceinline__ float bf2f(unsigned short h) {
  union { unsigned int u; float f; } v; v.u = ((unsigned int)h) << 16;
  return v.f;
}

// async global->LDS, 16B per lane; LDS dest is wave-uniform base + lane*16.
__device__ __forceinline__ void gload_lds16(const unsigned short* g, unsigned short* l) {
  __builtin_amdgcn_global_load_lds(
      (const __attribute__((address_space(1))) unsigned int*)g,
      (__attribute__((address_space(3))) unsigned int*)l, 16, 0, 0);
}

// ---------------------------------------------------------------------------
// Weight transpose + bf16 convert:  wt[n*K+k] = bf16(w[k*N+n])
// ---------------------------------------------------------------------------
__global__ void wtrans(const float* __restrict__ w, unsigned short* __restrict__ wt,
                       int K, int N) {
  int g = blockIdx.x * 256 + threadIdx.x;
  if (g < K * N) {
    int k = g / N, n = g % N;
    wt[(size_t)n * K + k] = f2bf(w[g]);
  }
}

// ---------------------------------------------------------------------------
// Depthwise 3x3 conv, SAME, with two-source add: dst = conv(a+b) + bias
// ---------------------------------------------------------------------------
__global__ void dwconv(const float* __restrict__ a, long bsA,
                       const float* __restrict__ b2, long bsB,
                       const float* __restrict__ w, const float* __restrict__ bias,
                       float* __restrict__ dst) {
  int g = blockIdx.x * 256 + threadIdx.x;   // < 16*128*3136
  int xx = g % 56;
  int yy = (g / 56) % 56;
  int c  = (g / NTOK) % 128;
  int b  = g / (NTOK * 128);
  const float* pa = a  + (size_t)b * bsA + (size_t)c * NTOK;
  const float* pb = b2 + (size_t)b * bsB + (size_t)c * NTOK;
  float acc = bias[c];
  #pragma unroll
  for (int ky = 0; ky < 3; ky++) {
    int y2 = yy + ky - 1;
    if (y2 < 0 || y2 >= 56) continue;
    #pragma unroll
    for (int kx = 0; kx < 3; kx++) {
      int x2 = xx + kx - 1;
      if (x2 < 0 || x2 >= 56) continue;
      acc += w[c * 9 + ky * 3 + kx] * (pa[y2 * 56 + x2] + pb[y2 * 56 + x2]);
    }
  }
  dst[((size_t)b * 128 + c) * NTOK + yy * 56 + xx] = acc;
}

// ---------------------------------------------------------------------------
// build_ln1 (tiled): gather NCHW pieces for 32 tokens into a [384][33] fp32
// LDS tile with coalesced global reads, per-token LN, coalesced writes of
// x_flat fp32 [T,384] and y bf16 [T,384].  1568 blocks (16 b x 98 tiles).
// ---------------------------------------------------------------------------
__global__ __launch_bounds__(256) void build_ln1(
    const float* __restrict__ x, const float* __restrict__ s1,
    const float* __restrict__ s2, const float* __restrict__ g,
    const float* __restrict__ bb, float* __restrict__ xflat,
    unsigned short* __restrict__ y) {
  __shared__ float tile[384 * 33];
  __shared__ float psum[8][32], psumsq[8][32];
  __shared__ float smean[32], srs[32];
  int blk = blockIdx.x;
  int b = blk / 98, n0 = (blk % 98) * 32;
  int t = threadIdx.x;
  int nl = t & 31, crow = t >> 5;        // staging: lane->n (coalesced), 8 c-rows/iter

  #pragma unroll 4
  for (int i = 0; i < 48; i++) {
    int c = i * 8 + crow;
    float v;
    if (c < 128)      v = x[((size_t)b * DIM + c) * NTOK + n0 + nl];
    else if (c < 256) v = s1[((size_t)b * 128 + (c - 128)) * NTOK + n0 + nl];
    else              v = s2[((size_t)b * 128 + (c - 256)) * NTOK + n0 + nl];
    tile[c * 33 + nl] = v;
  }
  __syncthreads();

  // per-token partial sums: 8 segments of 48 channels
  {
    int seg = t >> 5, tok = t & 31;
    float s = 0.f, sq = 0.f;
    #pragma unroll 8
    for (int cc = 0; cc < 48; cc++) {
      float v = tile[(seg * 48 + cc) * 33 + tok];
      s += v; sq += v * v;
    }
    psum[seg][tok] = s; psumsq[seg][tok] = sq;
  }
  __syncthreads();
  if (t < 32) {
    float s = 0.f, sq = 0.f;
    #pragma unroll
    for (int seg = 0; seg < 8; seg++) { s += psum[seg][t]; sq += psumsq[seg][t]; }
    float mean = s * (1.f / DIM);
    float var = sq * (1.f / DIM) - mean * mean;
    smean[t] = mean;
    srs[t] = rsqrtf(var + 1e-6f);
  }
  __syncthreads();

  // output: coalesced rows of x_flat / y
  #pragma unroll 4
  for (int i = 0; i < 48; i++) {
    int idx = i * 256 + t;               // < 12288 = 32*384
    int tok = idx / 384, c = idx - tok * 384;
    float v = tile[c * 33 + tok];
    size_t o = (size_t)(b * NTOK + n0 + tok) * DIM + c;
    xflat[o] = v;
    y[o] = f2bf((v - smean[tok]) * srs[tok] * g[c] + bb[c]);
  }
}

// ---------------------------------------------------------------------------
// Plain rowwise LN: fp32 [T,384] -> bf16 [T,384]
// ---------------------------------------------------------------------------
__global__ __launch_bounds__(256) void ln_rows(
    const float* __restrict__ in, const float* __restrict__ g,
    const float* __restrict__ bb, unsigned short* __restrict__ out) {
  int tkn = blockIdx.x * 4 + (threadIdx.x >> 6);
  int lane = threadIdx.x & 63;
  const float* row = in + (size_t)tkn * DIM;
  float v[6];
  float s = 0.f, sq = 0.f;
  #pragma unroll
  for (int i = 0; i < 6; i++) {
    int c = lane + i * 64;
    v[i] = row[c]; s += v[i]; sq += v[i] * v[i];
  }
  #pragma unroll
  for (int off = 32; off; off >>= 1) {
    s += __shfl_xor(s, off);
    sq += __shfl_xor(sq, off);
  }
  float mean = s * (1.f / DIM);
  float var = sq * (1.f / DIM) - mean * mean;
  float rs = rsqrtf(var + 1e-6f);
  #pragma unroll
  for (int i = 0; i < 6; i++) {
    int c = lane + i * 64;
    out[(size_t)tkn * DIM + c] = f2bf((v[i] - mean) * rs * g[c] + bb[c]);
  }
}

// ---------------------------------------------------------------------------
// 128-tile MFMA GEMM (m97 structure): C[M,N] = A[M,K] @ Bt[N,K]^T, bf16 in.
// MODE 0: store bf16 | MODE 1: +bias, exact GELU, bf16 | MODE 2: +bias+resid fp32
// ---------------------------------------------------------------------------
template<int BN, int MODE>
__global__ __launch_bounds__(256) void gemm128(
    const unsigned short* __restrict__ A, const unsigned short* __restrict__ Bt,
    const float* __restrict__ bias, const float* __restrict__ resid,
    void* __restrict__ out, int M, int N, int K) {
  constexpr int MT = (BN == 128) ? 4 : 2;
  constexpr int NT = 4;
  __shared__ __align__(16) unsigned short As[128 * 32];
  __shared__ __align__(16) unsigned short Bs[BN * 32];
  const int tid = threadIdx.x;
  const int w = tid >> 6, lane = tid & 63;
  const int quad = lane >> 4, r16 = lane & 15;
  const int row0 = blockIdx.y * 128, col0 = blockIdx.x * BN;
  const int wm = (BN == 128) ? (w >> 1) * 64 : w * 32;
  const int wn = (BN == 128) ? (w & 1) * 64 : 0;
  const int lrow = lane >> 2;
  const int lcol = (lane & 3) * 8;

  const unsigned short* aP0 = A + (size_t)(row0 + w * 32 + lrow) * K + lcol;
  const unsigned short* aP1 = aP0 + (size_t)16 * K;
  const unsigned short* bP0 = Bt + (size_t)(col0 + ((BN == 128) ? w * 32 : w * 16) + lrow) * K + lcol;
  const unsigned short* bP1 = bP0 + (size_t)16 * K;

  floatx4 acc[MT][NT] = {};

  for (int k0 = 0; k0 < K; k0 += 32) {
    gload_lds16(aP0 + k0, &As[(2 * w) * 512]);
    gload_lds16(aP1 + k0, &As[(2 * w + 1) * 512]);
    if (BN == 128) {
      gload_lds16(bP0 + k0, &Bs[(2 * w) * 512]);
      gload_lds16(bP1 + k0, &Bs[(2 * w + 1) * 512]);
    } else {
      gload_lds16(bP0 + k0, &Bs[w * 512]);
    }
    __syncthreads();
    short8 af[MT], bfr[NT];
    #pragma unroll
    for (int mi = 0; mi < MT; mi++)
      af[mi] = *(const short8*)(&As[(wm + mi * 16 + r16) * 32 + quad * 8]);
    #pragma unroll
    for (int ni = 0; ni < NT; ni++)
      bfr[ni] = *(const short8*)(&Bs[(wn + ni * 16 + r16) * 32 + quad * 8]);
    #pragma unroll
    for (int mi = 0; mi < MT; mi++)
      #pragma unroll
      for (int ni = 0; ni < NT; ni++)
        acc[mi][ni] = __builtin_amdgcn_mfma_f32_16x16x32_bf16(af[mi], bfr[ni], acc[mi][ni], 0, 0, 0);
    __syncthreads();
  }

  #pragma unroll
  for (int mi = 0; mi < MT; mi++)
    #pragma unroll
    for (int ni = 0; ni < NT; ni++)
      #pragma unroll
      for (int p = 0; p < 4; p++) {
        int row = row0 + wm + mi * 16 + quad * 4 + p;
        int col = col0 + wn + ni * 16 + r16;
        size_t idx = (size_t)row * N + col;
        float v = acc[mi][ni][p];
        if (MODE == 0) {
          ((unsigned short*)out)[idx] = f2bf(v);
        } else if (MODE == 1) {
          v += bias[col];
          v = 0.5f * v * (1.0f + erff(v * 0.70710678118654752f));
          ((unsigned short*)out)[idx] = f2bf(v);
        } else {
          v += bias[col] + resid[idx];
          ((float*)out)[idx] = v;
        }
      }
}

// ---------------------------------------------------------------------------
// XCA partials, NO atomics: 896 blocks = (b, h, chunk-of-448-tokens).
// Each block sums a 48x48 outer-product over its 448 tokens (7 LDS tiles of
// 64, [d][r] layout for ds_read_b128 over tokens) and writes a private slab
// S_part[chunk][bh][2304] + sq_part[chunk][b*768+...] with plain stores.
// ---------------------------------------------------------------------------
__global__ __launch_bounds__(256) void attn_partial(
    const unsigned short* __restrict__ qkv, float* __restrict__ S_part,
    float* __restrict__ sq_part) {
  __shared__ float qs[48 * 68];
  __shared__ float ks[48 * 68];
  int blk = blockIdx.x;                 // b*56 + h*7 + chunk
  int b = blk / 56, rem = blk % 56;
  int h = rem / 7, chunk = rem % 7;
  int t = threadIdx.x;
  int d0 = (t >> 4) * 3, e0 = (t & 15) * 3;

  floatx4 acc4[3][3] = {};
  floatx4 sqq4 = {}, sqk4 = {};

  for (int tile = 0; tile < 7; tile++) {
    __syncthreads();
    int tb = chunk * 448 + tile * 64;
    #pragma unroll
    for (int i = 0; i < 12; i++) {
      int idx = t + i * 256;            // < 3072
      int r = idx / 48, d = idx - r * 48;
      size_t ro = ((size_t)b * NTOK + tb + r) * 1152 + h * HD;
      qs[d * 68 + r] = bf2f(qkv[ro + d]);
      ks[d * 68 + r] = bf2f(qkv[ro + 384 + d]);
    }
    __syncthreads();
    #pragma unroll 4
    for (int r4 = 0; r4 < 16; r4++) {
      floatx4 q4[3], k4[3];
      #pragma unroll
      for (int j = 0; j < 3; j++) {
        q4[j] = *(const floatx4*)(&qs[(d0 + j) * 68 + r4 * 4]);
        k4[j] = *(const floatx4*)(&ks[(e0 + j) * 68 + r4 * 4]);
      }
      #pragma unroll
      for (int i = 0; i < 3; i++)
        #pragma unroll
        for (int j = 0; j < 3; j++)
          acc4[i][j] += q4[i] * k4[j];
    }
    // column sums of squares (waves 0,1 only; cheap)
    if (t < 48) {
      #pragma unroll 4
      for (int r4 = 0; r4 < 16; r4++) {
        floatx4 v = *(const floatx4*)(&qs[t * 68 + r4 * 4]);
        sqq4 += v * v;
      }
    } else if (t >= 64 && t < 112) {
      int e = t - 64;
      #pragma unroll 4
      for (int r4 = 0; r4 < 16; r4++) {
        floatx4 v = *(const floatx4*)(&ks[e * 68 + r4 * 4]);
        sqk4 += v * v;
      }
    }
  }

  int bh = b * NH + h;
  float* Sp = S_part + ((size_t)chunk * 128 + bh) * 2304;
  #pragma unroll
  for (int i = 0; i < 3; i++)
    #pragma unroll
    for (int j = 0; j < 3; j++)
      Sp[(d0 + i) * 48 + e0 + j] = acc4[i][j][0] + acc4[i][j][1] + acc4[i][j][2] + acc4[i][j][3];
  if (t < 48)
    sq_part[(size_t)chunk * 12288 + b * 768 + h * HD + t] = sqq4[0] + sqq4[1] + sqq4[2] + sqq4[3];
  else if (t >= 64 && t < 112)
    sq_part[(size_t)chunk * 12288 + b * 768 + 384 + h * HD + (t - 64)] = sqk4[0] + sqk4[1] + sqk4[2] + sqk4[3];
}

// ---------------------------------------------------------------------------
// Sum 7 S_part slabs, apply 1/(|q||k|), row softmax -> attnb[bh][48][48].
// ---------------------------------------------------------------------------
__global__ __launch_bounds__(256) void attn_finish(
    const float* __restrict__ S_part, const float* __restrict__ sq_part,
    float* __restrict__ attnb) {
  __shared__ float qn[48], kn[48];
  __shared__ float Ss[48 * 49];
  int bh = blockIdx.x, b = bh >> 3, h = bh & 7;
  int t = threadIdx.x;
  if (t < 48) {
    float s = 0.f;
    #pragma unroll
    for (int p = 0; p < 7; p++) s += sq_part[(size_t)p * 12288 + b * 768 + h * HD + t];
    qn[t] = fmaxf(sqrtf(s), 1e-12f);
  } else if (t >= 64 && t < 112) {
    int e = t - 64;
    float s = 0.f;
    #pragma unroll
    for (int p = 0; p < 7; p++) s += sq_part[(size_t)p * 12288 + b * 768 + 384 + h * HD + e];
    kn[e] = fmaxf(sqrtf(s), 1e-12f);
  }
  __syncthreads();
  #pragma unroll
  for (int j = 0; j < 9; j++) {
    int idx = j * 256 + t;              // < 2304, coalesced over t
    float s = 0.f;
    #pragma unroll
    for (int p = 0; p < 7; p++) s += S_part[((size_t)p * 128 + bh) * 2304 + idx];
    int d = idx / 48, e = idx - d * 48;
    Ss[d * 49 + e] = s / (qn[d] * kn[e]);
  }
  __syncthreads();
  if (t < 48) {
    float m = -1e30f;
    for (int e = 0; e < 48; e++) m = fmaxf(m, Ss[t * 49 + e]);
    float ssum = 0.f;
    float ex[48];
    for (int e = 0; e < 48; e++) { ex[e] = expf(Ss[t * 49 + e] - m); ssum += ex[e]; }
    float inv = 1.f / ssum;
    float* op = attnb + (size_t)bh * 2304 + t * 48;
    for (int e = 0; e < 48; e++) op[e] = ex[e] * inv;
  }
}

// ---------------------------------------------------------------------------
// y_attn[b,n,h*48+d] = sum_e attn[b,h,d,e] * v[b,n,h,e]   -> bf16
// 6272 blocks = (b,h,chunk-of-64).  One token per lane; wave w owns d range
// [12w,12w+12) so att-row LDS reads are wave-uniform broadcasts.
// ---------------------------------------------------------------------------
__global__ __launch_bounds__(256) void attn_apply(
    const unsigned short* __restrict__ qkv, const float* __restrict__ attnb,
    unsigned short* __restrict__ yat) {
  __shared__ float at[48 * 52];
  __shared__ float vs[64 * 56];
  int bh = blockIdx.x / 49, chunk = blockIdx.x % 49;
  int b = bh >> 3, h = bh & 7;
  int t = threadIdx.x;
  int lane = t & 63, w = t >> 6;
  #pragma unroll
  for (int i = 0; i < 9; i++) {
    int idx = t + i * 256;
    if (idx < 2304) at[(idx / 48) * 52 + idx % 48] = attnb[(size_t)bh * 2304 + idx];
  }
  #pragma unroll
  for (int i = 0; i < 12; i++) {
    int idx = t + i * 256;              // < 3072
    int r = idx / 48, d = idx - r * 48;
    vs[r * 56 + d] = bf2f(qkv[((size_t)b * NTOK + chunk * 64 + r) * 1152 + 768 + h * HD + d]);
  }
  __syncthreads();
  floatx4 v4[12];
  #pragma unroll
  for (int j = 0; j < 12; j++)
    v4[j] = *(const floatx4*)(&vs[lane * 56 + j * 4]);
  float r[12];
  #pragma unroll
  for (int dd = 0; dd < 12; dd++) {
    int d = w * 12 + dd;
    floatx4 a = {};
    #pragma unroll
    for (int j = 0; j < 12; j++)
      a += *(const floatx4*)(&at[d * 52 + j * 4]) * v4[j];
    r[dd] = a[0] + a[1] + a[2] + a[3];
  }
  size_t wo = ((size_t)b * NTOK + chunk * 64 + lane) * DIM + h * HD + w * 12;
  unsigned int* op = (unsigned int*)(yat + wo);
  #pragma unroll
  for (int j = 0; j < 6; j++)
    op[j] = (unsigned int)f2bf(r[2 * j]) | ((unsigned int)f2bf(r[2 * j + 1]) << 16);
}

// ---------------------------------------------------------------------------
// Final transpose: [B,N,C] fp32 -> [B,C,N] fp32 (32x32 LDS tiles)
// ---------------------------------------------------------------------------
__global__ __launch_bounds__(256) void transpose_out(const float* __restrict__ in,
                                                     float* __restrict__ out) {
  __shared__ float tile[32][33];
  int b = blockIdx.z, ct = blockIdx.y, nt = blockIdx.x;
  int t = threadIdx.x;
  int cc = t & 31, rr = t >> 5;
  #pragma unroll
  for (int i = 0; i < 4; i++) {
    int nn = rr + i * 8;
    tile[nn][cc] = in[((size_t)b * NTOK + nt * 32 + nn) * DIM + ct * 32 + cc];
  }
  __syncthreads();
  #pragma unroll
  for (int i = 0; i < 4; i++) {
    int c2 = rr + i * 8;
    out[((size_t)b * DIM + ct * 32 + c2) * NTOK + nt * 32 + cc] = tile[cc][c2];
  }
}

// ---------------------------------------------------------------------------
extern "C" void kernel_launch(void* const* d_in, const int* in_sizes, int n_in,
                              void* d_out, int out_size, void* d_ws, size_t ws_size,
                              hipStream_t stream) {
  const float* x       = (const float*)d_in[0];
  const float* dw_w0   = (const float*)d_in[1];
  const float* dw_b0   = (const float*)d_in[2];
  const float* dw_w1   = (const float*)d_in[3];
  const float* dw_b1   = (const float*)d_in[4];
  const float* ln1_g   = (const float*)d_in[5];
  const float* ln1_b   = (const float*)d_in[6];
  const float* qkv_w   = (const float*)d_in[7];
  const float* proj_w  = (const float*)d_in[8];
  const float* proj_b  = (const float*)d_in[9];
  const float* ln2_g   = (const float*)d_in[10];
  const float* ln2_b   = (const float*)d_in[11];
  const float* mlp1_dw = (const float*)d_in[12];
  const float* mlp1_uw = (const float*)d_in[13];
  const float* mlp1_ub = (const float*)d_in[14];
  const float* mlp2_dw = (const float*)d_in[15];
  const float* mlp2_uw = (const float*)d_in[16];
  const float* mlp2_ub = (const float*)d_in[17];
  float* out = (float*)d_out;
  char* ws = (char*)d_ws;

  // ---- workspace layout, lifetime-aliased; peak 235,094,016 B (~224 MiB) ----
  float*          xflat = (float*)(ws + 0);                    // 77,070,336  alive 3-8
  unsigned short* qkvb  = (unsigned short*)(ws + 77070336);    // 115,605,504 alive 4-7
  float*          s1ws  = (float*)(ws + 77070336);             // 25,690,112  alive 1-3
  float*          s2ws  = (float*)(ws + 102760448);            // 25,690,112  alive 2-3
  unsigned short* ybf   = (unsigned short*)(ws + 192675840);   // 38,535,168  alive 3-4
  float*          S_part  = (float*)(ws + 192675840);          //  8,257,536  alive 5-6
  float*          sq_part = (float*)(ws + 200933376);          //    344,064  alive 5-6
  unsigned short* yat   = (unsigned short*)(ws + 192675840);   // 38,535,168  alive 7-8
  float*          xres  = (float*)(ws + 77070336);             // 77,070,336  alive 8-13
  unsigned short* zbf   = (unsigned short*)(ws + 0);           // 38,535,168  alive 9-10
  unsigned short* h1    = (unsigned short*)(ws + 38535168);    // 19,267,584  alive 10-11
  unsigned short* h3    = (unsigned short*)(ws + 57802752);    // 19,267,584  alive 11-12
  unsigned short* h2    = (unsigned short*)(ws + 154140672);   // 77,070,336  alive 11 (half-T)
  unsigned short* qkvT  = (unsigned short*)(ws + 231211008);   //    884,736
  unsigned short* projT = (unsigned short*)(ws + 232095744);   //    294,912
  unsigned short* m1dT  = (unsigned short*)(ws + 232390656);   //    147,456
  unsigned short* m1uT  = (unsigned short*)(ws + 232538112);   //    589,824
  unsigned short* m2dT  = (unsigned short*)(ws + 233127936);   //    589,824
  unsigned short* m2uT  = (unsigned short*)(ws + 233717760);   //    147,456
  float*          attnb = (float*)(ws + 233914368);            //  1,179,648 -> 235,094,016

  // weights -> [N,K] bf16
  wtrans<<<1728, 256, 0, stream>>>(qkv_w, qkvT, 384, 1152);
  wtrans<<<576, 256, 0, stream>>>(proj_w, projT, 384, 384);
  wtrans<<<288, 256, 0, stream>>>(mlp1_dw, m1dT, 384, 192);
  wtrans<<<1152, 256, 0, stream>>>(mlp1_uw, m1uT, 192, 1536);
  wtrans<<<1152, 256, 0, stream>>>(mlp2_dw, m2dT, 1536, 192);
  wtrans<<<288, 256, 0, stream>>>(mlp2_uw, m2uT, 192, 384);

  // depthwise chain: s1' = conv(s1+s0), s2' = conv(s2+s1')
  dwconv<<<25088, 256, 0, stream>>>(x + 128 * NTOK, (long)DIM * NTOK,
                                    x, (long)DIM * NTOK, dw_w0, dw_b0, s1ws);
  dwconv<<<25088, 256, 0, stream>>>(x + 256 * NTOK, (long)DIM * NTOK,
                                    s1ws, (long)128 * NTOK, dw_w1, dw_b1, s2ws);

  // gather + LN1 (tiled, coalesced)
  build_ln1<<<1568, 256, 0, stream>>>(x, s1ws, s2ws, ln1_g, ln1_b, xflat, ybf);

  // qkv = y @ qkv_w   [50176,1152] bf16
  gemm128<128, 0><<<dim3(9, 392), 256, 0, stream>>>(ybf, qkvT, nullptr, nullptr,
                                                    qkvb, TTOK, 1152, 384);
  // XCA: non-atomic partials (896 blocks) -> finish (128 blocks)
  attn_partial<<<NB * NH * 7, 256, 0, stream>>>(qkvb, S_part, sq_part);
  attn_finish<<<NB * NH, 256, 0, stream>>>(S_part, sq_part, attnb);
  // y_attn = attn @ v  -> bf16 [T,384]
  attn_apply<<<NB * NH * 49, 256, 0, stream>>>(qkvb, attnb, yat);

  // x_res = x_flat + y_attn @ proj_w + proj_b   (fp32)
  gemm128<128, 2><<<dim3(3, 392), 256, 0, stream>>>(yat, projT, proj_b, xflat,
                                                    xres, TTOK, 384, 384);
  // z = LN2(x_res)  bf16
  ln_rows<<<12544, 256, 0, stream>>>(xres, ln2_g, ln2_b, zbf);
  // MLP down: h1 = z @ mlp1_dw  [T,192]
  gemm128<64, 0><<<dim3(3, 392), 256, 0, stream>>>(zbf, m1dT, nullptr, nullptr,
                                                   h1, TTOK, 192, 384);
  // MLP mid in two half-T passes through one 77MB h2 buffer
  for (int half = 0; half < 2; half++) {
    const unsigned short* h1p = h1 + (size_t)half * 25088 * 192;
    unsigned short* h3p = h3 + (size_t)half * 25088 * 192;
    gemm128<128, 1><<<dim3(12, 196), 256, 0, stream>>>(h1p, m1uT, mlp1_ub, nullptr,
                                                       h2, 25088, 1536, 192);
    gemm128<64, 0><<<dim3(3, 196), 256, 0, stream>>>(h2, m2dT, nullptr, nullptr,
                                                     h3p, 25088, 192, 1536);
  }
  // out_flat = x_res + h3 @ mlp2_uw + b   (in-place over x_res)
  gemm128<128, 2><<<dim3(3, 392), 256, 0, stream>>>(h3, m2uT, mlp2_ub, xres,
                                                    xres, TTOK, 384, 192);
  // [B,N,C] -> [B,C,H,W]
  transpose_out<<<dim3(98, 12, 16), 256, 0, stream>>>(xres, out);
}